// Round 7
// baseline (45.527 us; speedup 1.0000x reference)
//
#include <hip/hip_runtime.h>
#include <limits.h>

#define DIM 128
#define NVOX 131072
#define NQ 131072
#define NCELL (2 * DIM * DIM * DIM)        // 4,194,304 cells
#define BITWORDS (NCELL / 64)              // 65,536 x 8B = 512 KB bitmap

// d_out float layout (concatenated reference outputs)
#define QF_OFF  0
#define IDX_OFF (NQ * 128)                 // 16,777,216
#define WV_OFF  (IDX_OFF + NQ * 8)         // 17,825,792
#define ACC_OFF (WV_OFF + NQ * 8)          // 18,874,368

#define SHIFT_BLOCKS 64
// d_ws layout: sp[6][64] @0, bitmap @4096 (512KB), idx grid @528384 (16MB)

typedef float vf2 __attribute__((ext_vector_type(2)));

#define WREDUCE_MIN(mv)                                       \
    _Pragma("unroll")                                         \
    for (int off = 32; off >= 1; off >>= 1)                   \
        mv = min(mv, __shfl_xor(mv, off, 64));

// cell index from UNSHIFTED coords (b in bit 21, x 14, y 7, z 0)
__device__ __forceinline__ int cell_of(int b, int x, int y, int z) {
    return (b << 21) + (x << 14) + (y << 7) + z;
}

// ---- prep: clear bitmap/accum, clear ONLY touched idx cells, coord min ----
__global__ __launch_bounds__(256) void k_prep(const int* __restrict__ coords,
                                              int* __restrict__ sp,
                                              unsigned long long* __restrict__ bitmap,
                                              int* __restrict__ idxg,
                                              float* __restrict__ accum) {
    int tid = blockIdx.x * 256 + threadIdx.x;          // grid = 512 blocks -> 131072
    int4 c = ((const int4*)coords)[tid];
    idxg[cell_of(c.x, c.y, c.z, c.w)] = -1;            // scattered pre-clear
    if (tid < BITWORDS) bitmap[tid] = 0ull;
    accum[tid] = 0.f;

    if (blockIdx.x < SHIFT_BLOCKS) {                   // per-batch component mins
        __shared__ int sm[4][6];
        int i0 = blockIdx.x * 256 + threadIdx.x;
        int sstride = SHIFT_BLOCKS * 256;
        int m0 = INT_MAX, m1 = INT_MAX, m2 = INT_MAX;
        int m3 = INT_MAX, m4 = INT_MAX, m5 = INT_MAX;
        const int4* c4 = (const int4*)coords;
        for (int i = i0; i < NVOX; i += sstride) {
            int4 v = c4[i];
            if (v.x == 0) { m0 = min(m0, v.y); m1 = min(m1, v.z); m2 = min(m2, v.w); }
            else          { m3 = min(m3, v.y); m4 = min(m4, v.z); m5 = min(m5, v.w); }
        }
        WREDUCE_MIN(m0) WREDUCE_MIN(m1) WREDUCE_MIN(m2)
        WREDUCE_MIN(m3) WREDUCE_MIN(m4) WREDUCE_MIN(m5)
        int wave = threadIdx.x >> 6;
        if ((threadIdx.x & 63) == 0) {
            sm[wave][0] = m0; sm[wave][1] = m1; sm[wave][2] = m2;
            sm[wave][3] = m3; sm[wave][4] = m4; sm[wave][5] = m5;
        }
        __syncthreads();
        if (threadIdx.x == 0) {
            #pragma unroll
            for (int k = 0; k < 6; ++k)
                sp[k * SHIFT_BLOCKS + blockIdx.x] =
                    min(min(sm[0][k], sm[1][k]), min(sm[2][k], sm[3][k]));
        }
    }
}

// ---- build: set occupancy bit + max voxel index (last-write-wins == max) ----
__global__ __launch_bounds__(256) void k_build(const int* __restrict__ coords,
                                               unsigned long long* __restrict__ bitmap,
                                               int* __restrict__ idxg) {
    int i = blockIdx.x * 256 + threadIdx.x;            // grid = 512 blocks
    int4 c = ((const int4*)coords)[i];
    int cell = cell_of(c.x, c.y, c.z, c.w);
    atomicOr(&bitmap[cell >> 6], 1ull << (cell & 63));
    atomicMax(&idxg[cell], i);
}

// ---- per-block: reduce the 64 partial mins into sh[6] (wave 0), sync ----
__device__ __forceinline__ void load_shift(const int* __restrict__ sp, int* sh) {
    if (threadIdx.x < 64) {
        int l = threadIdx.x;
        #pragma unroll
        for (int k = 0; k < 6; ++k) {
            int v = sp[k * SHIFT_BLOCKS + l];
            WREDUCE_MIN(v)
            if (l == 0) sh[k] = v;
        }
    }
    // no sync here; caller syncs after phase 1 LDS writes
}

// -------- main: thread-per-query probe phase (MLP ~16 loads/thread), --------
// -------- LDS handoff, scalar-loop gather phase. Zero shuffles.      --------
__global__ __launch_bounds__(256) void k_query(
    const float* __restrict__ qpts, const float* __restrict__ feats,
    const unsigned long long* __restrict__ bitmap, const int* __restrict__ idxg,
    const int* __restrict__ sp, float* __restrict__ out) {
    __shared__ int sh[6];
    __shared__ int2  s_iw[256 * 8];   // 16 KB: {idx or -1, wv bits}
    __shared__ uint2 s_mi[256];       // 2 KB:  {gather mask, inv bits}
    load_shift(sp, sh);
    __syncthreads();                  // sh ready

    int t = threadIdx.x;
    int q = blockIdx.x * 256 + t;

    // ---- phase 1: all 8 corners of this thread's query ----
    float4 qp = ((const float4*)qpts)[q];
    int qb = (int)qp.x;
    int shx = sh[qb * 3 + 0], shy = sh[qb * 3 + 1], shz = sh[qb * 3 + 2];
    float fx0 = floorf(qp.y), fy0 = floorf(qp.z), fz0 = floorf(qp.w);
    float fx = qp.y - fx0, fy = qp.z - fy0, fz = qp.w - fz0;
    int ix = (int)fx0, iy = (int)fy0, iz = (int)fz0;

    int cells[8]; bool okc[8]; float wc[8];
#pragma unroll
    for (int k = 0; k < 8; ++k) {
        const int ox = (k >> 2) & 1, oy = (k >> 1) & 1, oz = k & 1;
        int ux = ix + ox, uy = iy + oy, uz = iz + oz;
        okc[k] = ((unsigned)(ux - shx) < DIM) && ((unsigned)(uy - shy) < DIM) &&
                 ((unsigned)(uz - shz) < DIM) &&
                 ((unsigned)ux < DIM) && ((unsigned)uy < DIM) && ((unsigned)uz < DIM);
        int cx = min(max(ux, 0), DIM - 1);
        int cy = min(max(uy, 0), DIM - 1);
        int cz = min(max(uz, 0), DIM - 1);
        cells[k] = cell_of(qb, cx, cy, cz);
        wc[k] = (ox ? fx : 1.f - fx) * (oy ? fy : 1.f - fy) * (oz ? fz : 1.f - fz);
    }
    unsigned long long wb[8];
#pragma unroll
    for (int k = 0; k < 8; ++k) wb[k] = bitmap[cells[k] >> 6];   // 8 in flight
    bool val[8];
#pragma unroll
    for (int k = 0; k < 8; ++k)
        val[k] = okc[k] && (((wb[k] >> (cells[k] & 63)) & 1ull) != 0ull);
    int idxk[8];
#pragma unroll
    for (int k = 0; k < 8; ++k) idxk[k] = val[k] ? idxg[cells[k]] : -1;  // masked, independent

    float wsum = 0.f; unsigned msk = 0u;
#pragma unroll
    for (int k = 0; k < 8; ++k) {
        float wv = val[k] ? wc[k] : 0.f;
        wsum += wv;
        if (wv != 0.f) {
            msk |= 1u << k;
            atomicAdd(out + ACC_OFF + idxk[k], wv);
        }
        s_iw[t * 8 + k] = make_int2(idxk[k], __float_as_int(wv));
    }
    float inv = __builtin_amdgcn_rcpf(fmaxf(wsum, 1e-8f));
    s_mi[t] = make_uint2(msk, __float_as_uint(inv));
    __syncthreads();

    // ---- phase 2: side outputs, flat coalesced copies from LDS ----
    size_t sbase = (size_t)blockIdx.x * 2048;
#pragma unroll
    for (int j = 0; j < 8; ++j) {
        int2 iw = s_iw[j * 256 + t];
        __builtin_nontemporal_store((float)iw.x, out + IDX_OFF + sbase + j * 256 + t);
        __builtin_nontemporal_store(__int_as_float(iw.y), out + WV_OFF + sbase + j * 256 + t);
    }

    // ---- phase 3: wave-per-64-queries gather; scalar mask loop ----
    int lane = t & 63;
    int wq0 = (t >> 6) * 64;
    const vf2* f2 = (const vf2*)feats;
    vf2* qf = (vf2*)(out + QF_OFF);
    size_t qgbase = (size_t)blockIdx.x * 256;
    for (int g = 0; g < 64; ++g) {
        int qq = wq0 + g;
        uint2 mi = s_mi[qq];
        unsigned m = __builtin_amdgcn_readfirstlane(mi.x);   // wave-uniform -> SGPR
        vf2 acc = (vf2){0.f, 0.f};
        while (m) {                                          // scalar loop, ~0.25 iters avg
            int j = __ffs(m) - 1; m &= m - 1;
            int2 iw = s_iw[qq * 8 + j];
            int row = __builtin_amdgcn_readfirstlane(iw.x);  // SGPR base for gather
            float wv = __int_as_float(iw.y);
            vf2 fv = f2[(size_t)row * 64 + lane];
            acc.x = fmaf(wv, fv.x, acc.x);
            acc.y = fmaf(wv, fv.y, acc.y);
        }
        float iv = __uint_as_float(mi.y);
        vf2 r;
        r.x = acc.x * iv;
        r.y = acc.y * iv;
        __builtin_nontemporal_store(r, qf + (qgbase + qq) * 64 + lane);
    }
}

extern "C" void kernel_launch(void* const* d_in, const int* in_sizes, int n_in,
                              void* d_out, int out_size, void* d_ws, size_t ws_size,
                              hipStream_t stream) {
    const int*   coords = (const int*)d_in[0];
    const float* feats  = (const float*)d_in[1];
    const float* qpts   = (const float*)d_in[2];
    float* out = (float*)d_out;

    int* sp = (int*)d_ws;                                          // [6][64]
    unsigned long long* bitmap = (unsigned long long*)((char*)d_ws + 4096);  // 512 KB
    int* idxg = (int*)((char*)d_ws + 4096 + BITWORDS * 8);         // 16 MB

    k_prep<<<NVOX / 256, 256, 0, stream>>>(coords, sp, bitmap, idxg, out + ACC_OFF);
    k_build<<<NVOX / 256, 256, 0, stream>>>(coords, bitmap, idxg);
    k_query<<<NQ / 256, 256, 0, stream>>>(qpts, feats, bitmap, idxg, sp, out);
}